// Round 1
// 2374.796 us; speedup vs baseline: 1.2191x; 1.2191x over previous
//
#include <hip/hip_runtime.h>

#define Bv 2
#define Cv 768
#define Hv 256
#define Wv 256
#define WHv 129
#define NBv 8
#define BSv 96

typedef float2 cplx;
typedef __bf16 bf16x8 __attribute__((ext_vector_type(8)));
typedef float f32x4 __attribute__((ext_vector_type(4)));

#define MFMA(A, B, C) __builtin_amdgcn_mfma_f32_16x16x32_bf16((A), (B), (C), 0, 0, 0)

__device__ __forceinline__ unsigned brev8(unsigned v) { return __brev(v) >> 24; }

// Each wave fills the whole table itself -> no cross-wave dependency, no barrier.
__device__ __forceinline__ void fill_tw(cplx* tw, int lane) {
#pragma unroll
  for (int r = 0; r < 4; ++r) {
    int m = lane + (r << 6);
    float s, c;
    __sincosf((float)m * (-6.283185307179586f / 256.0f), &s, &c);
    tw[m] = make_float2(c, s);  // e^{-2*pi*i*m/256}
  }
}

// In-place radix-2 DIT 256-pt FFT on one LDS row, executed by one 64-lane wave.
template <int INV>
__device__ __forceinline__ void fft256(cplx* row, const cplx* tw, int lane) {
#pragma unroll
  for (int len = 2; len <= 256; len <<= 1) {
    const int half = len >> 1;
#pragma unroll
    for (int r = 0; r < 2; ++r) {
      int b = lane + (r << 6);      // butterfly id 0..127
      int j = b & (half - 1);
      int i0 = 2 * b - j;           // = (b/half)*len + j
      int i1 = i0 + half;
      cplx u = row[i0];
      cplx v = row[i1];
      cplx w = tw[j * (256 / len)];
      float wy = INV ? -w.y : w.y;
      float vr = v.x * w.x - v.y * wy;
      float vi = v.x * wy + v.y * w.x;
      row[i0] = make_float2(u.x + vr, u.y + vi);
      row[i1] = make_float2(u.x - vr, u.y - vi);
    }
  }
}

// K1: row rfft (real 256 -> 129 complex), write transposed F[b,c,w,h].
__global__ __launch_bounds__(512) void k_fwd_row(const float* __restrict__ x,
                                                 cplx* __restrict__ F) {
  __shared__ cplx buf[8][257];
  __shared__ cplx tw[256];
  int tid = threadIdx.x;
  int wv = tid >> 6, lane = tid & 63;
  fill_tw(tw, lane);
  int r0 = blockIdx.x * 8;
  int bc = r0 >> 8;      // image index (b*C + c)
  int h0 = r0 & 255;     // first row in this block
  const float* xr = x + ((size_t)bc * 256 + (size_t)(h0 + wv)) * 256;
#pragma unroll
  for (int r = 0; r < 4; ++r) {
    int idx = lane + (r << 6);
    buf[wv][brev8(idx)] = make_float2(xr[idx], 0.0f);
  }
  fft256<0>(&buf[wv][0], tw, lane);
  __syncthreads();  // cross-wave transposed write below
  for (int e = tid; e < WHv * 8; e += 512) {
    int w = e >> 3, hh = e & 7;
    F[((size_t)bc * WHv + w) * 256 + h0 + hh] = buf[hh][w];
  }
}

// K2/K4: in-place complex FFT along H (columns are contiguous in F layout).
template <int INV>
__global__ __launch_bounds__(512) void k_col_fft(cplx* __restrict__ F) {
  __shared__ cplx buf[8][256];
  __shared__ cplx tw[256];
  int tid = threadIdx.x;
  int wv = tid >> 6, lane = tid & 63;
  fill_tw(tw, lane);
  size_t base = ((size_t)blockIdx.x * 8 + wv) * 256;
#pragma unroll
  for (int r = 0; r < 4; ++r) {
    int idx = lane + (r << 6);
    buf[wv][brev8(idx)] = F[base + idx];
  }
  fft256<INV>(&buf[wv][0], tw, lane);
#pragma unroll
  for (int r = 0; r < 4; ++r) {
    int idx = lane + (r << 6);
    F[base + idx] = buf[wv][idx];
  }
}

// Prep: split w1/w2 into hi/lo bf16 and swizzle into MFMA A-fragment order.
// Layout: [L][k][ks][m][term(rH,rL,iH,iL)][lane][j]  (j = 8 contiguous K elems)
// value = W[k][i][o] with i = ks*32 + (lane>>4)*8 + j, o = m*16 + (lane&15).
// Forward ortho scale 1/256 folded into W1.
__global__ __launch_bounds__(256) void k_prep(const float* __restrict__ w1,
                                              const float* __restrict__ w2,
                                              __bf16* __restrict__ wp) {
  int idx = blockIdx.x * 256 + threadIdx.x;
  int j = idx & 7;
  int lane = (idx >> 3) & 63;
  int term = (idx >> 9) & 3;
  int t2 = idx >> 11;
  int m = t2 % 6; t2 /= 6;
  int ks = t2 % 3; t2 /= 3;
  int k = t2 & 7;
  int L = t2 >> 3;
  int i = ks * 32 + ((lane >> 4) << 3) + j;
  int o = (m << 4) + (lane & 15);
  const float* src = L ? w2 : w1;
  float v = src[(((size_t)k * BSv + i) * BSv + o) * 2 + (term >> 1)];
  if (L == 0) v *= (1.0f / 256.0f);
  __bf16 h = (__bf16)v;
  __bf16 r = (term & 1) ? (__bf16)(v - (float)h) : h;
  wp[idx] = r;
}

// One layer of the complex MLP: acc = W^T * A over K=96, split-bf16 MFMA.
// T holds the input tile [96 K][64 h] (pad 65 -> fragment ds_reads are 2-way/free).
__device__ __forceinline__ void mlp_layer(const cplx (*T)[65],
                                          const bf16x8* __restrict__ q0,
                                          int lane, int lg, int hcol,
                                          f32x4 accr[6], f32x4 acci[6]) {
#pragma unroll
  for (int m = 0; m < 6; ++m) {
    accr[m] = (f32x4){0.0f, 0.0f, 0.0f, 0.0f};
    acci[m] = (f32x4){0.0f, 0.0f, 0.0f, 0.0f};
  }
#pragma unroll
  for (int ks = 0; ks < 3; ++ks) {
    bf16x8 arh, arl, aih, ail, aihn, ailn;
    int i0 = ks * 32 + (lg << 3);
#pragma unroll
    for (int j = 0; j < 8; ++j) {
      cplx a = T[i0 + j][hcol];
      __bf16 rh = (__bf16)a.x;
      float rhf = (float)rh;
      __bf16 rl = (__bf16)(a.x - rhf);
      __bf16 ih = (__bf16)a.y;
      float ihf = (float)ih;
      __bf16 il = (__bf16)(a.y - ihf);
      arh[j] = rh;  arl[j] = rl;
      aih[j] = ih;  ail[j] = il;
      aihn[j] = (__bf16)(0.0f - ihf);      // exact negation of hi
      ailn[j] = (__bf16)(ihf - a.y);       // exact negation of lo
    }
    const bf16x8* q = q0 + ks * (6 * 4 * 64) + lane;
#pragma unroll
    for (int m = 0; m < 6; ++m) {
      bf16x8 wrh = q[(m * 4 + 0) * 64];
      bf16x8 wrl = q[(m * 4 + 1) * 64];
      bf16x8 wih = q[(m * 4 + 2) * 64];
      bf16x8 wil = q[(m * 4 + 3) * 64];
      f32x4 ar = accr[m], ai = acci[m];
      // Or = Wr*Ar - Wi*Ai   (3-term split each)
      ar = MFMA(wrh, arh, ar);
      ar = MFMA(wrh, arl, ar);
      ar = MFMA(wrl, arh, ar);
      ar = MFMA(wih, aihn, ar);
      ar = MFMA(wih, ailn, ar);
      ar = MFMA(wil, aihn, ar);
      // Oi = Wr*Ai + Wi*Ar
      ai = MFMA(wrh, aih, ai);
      ai = MFMA(wrh, ail, ai);
      ai = MFMA(wrl, aih, ai);
      ai = MFMA(wih, arh, ai);
      ai = MFMA(wih, arl, ai);
      ai = MFMA(wil, arh, ai);
      accr[m] = ar;
      acci[m] = ai;
    }
  }
}

// K3: per-mode block-diagonal complex MLP via split-bf16 MFMA, in place on F.
// block = 256 threads = 4 waves; wave wv owns h-cols [16*wv, 16*wv+16).
__global__ __launch_bounds__(256) void k_mix(cplx* __restrict__ F,
                                             const __bf16* __restrict__ WPg,
                                             const float* __restrict__ b1,
                                             const float* __restrict__ b2) {
  __shared__ cplx T[BSv][65];  // 49920 B
  int bid = blockIdx.x;
  int ht = bid & 3; bid >>= 2;
  int w = bid % WHv; bid /= WHv;
  int k = bid & 7;
  int b = bid >> 3;
  int tid = threadIdx.x;
  int lane = tid & 63;
  int wv = __builtin_amdgcn_readfirstlane(tid >> 6);
  int lg = lane >> 4;
  int hcol = (wv << 4) + (lane & 15);
  int h0 = ht << 6;
  size_t base = ((size_t)(b * Cv + k * BSv) * WHv + w) * 256 + h0;
  const size_t cstride = (size_t)WHv * 256;

  // Stage A tile (96 channels x 64 h). 1/256 ortho scale is folded into W1.
  for (int e = tid; e < BSv * 64; e += 256) {
    int i = e >> 6, hh = e & 63;
    T[i][hh] = F[base + (size_t)i * cstride + hh];
  }
  __syncthreads();

  const bf16x8* WPv = (const bf16x8*)WPg;
  f32x4 accr[6], acci[6];

  // ---- layer 1 ----
  mlp_layer(T, WPv + (size_t)k * (3 * 6 * 4 * 64), lane, lg, hcol, accr, acci);
  __syncthreads();  // all waves done reading A tile

  // bias + relu -> o1 back into T  (D layout: o = m*16 + lg*4 + r, col = hcol)
  const cplx* B1 = (const cplx*)b1 + k * BSv;
#pragma unroll
  for (int m = 0; m < 6; ++m) {
#pragma unroll
    for (int r = 0; r < 4; ++r) {
      int o = (m << 4) + (lg << 2) + r;
      cplx bb = B1[o];
      T[o][hcol] = make_float2(fmaxf(accr[m][r] + bb.x, 0.0f),
                               fmaxf(acci[m][r] + bb.y, 0.0f));
    }
  }
  __syncthreads();  // o1 visible to all

  // ---- layer 2 ----
  mlp_layer(T, WPv + (size_t)(8 + k) * (3 * 6 * 4 * 64), lane, lg, hcol, accr, acci);

  const cplx* B2 = (const cplx*)b2 + k * BSv;
#pragma unroll
  for (int m = 0; m < 6; ++m) {
#pragma unroll
    for (int r = 0; r < 4; ++r) {
      int o = (m << 4) + (lg << 2) + r;
      cplx bb = B2[o];
      float re = accr[m][r] + bb.x;
      float im = acci[m][r] + bb.y;
      re = copysignf(fmaxf(fabsf(re) - 0.01f, 0.0f), re);  // softshrink
      im = copysignf(fmaxf(fabsf(im) - 0.01f, 0.0f), im);
      F[base + (size_t)o * cstride + hcol] = make_float2(re, im);
    }
  }
}

// K5: Hermitian-extend along w, inverse FFT, real part * 1/256 + residual.
__global__ __launch_bounds__(512) void k_inv_row(const cplx* __restrict__ F,
                                                 const float* __restrict__ x,
                                                 float* __restrict__ out) {
  __shared__ cplx buf[8][257];
  __shared__ cplx tw[256];
  int tid = threadIdx.x;
  int wv = tid >> 6, lane = tid & 63;
  fill_tw(tw, lane);
  int r0 = blockIdx.x * 8;
  int bc = r0 >> 8;
  int h0 = r0 & 255;
  // gather spectrum tile [129 w][8 h], scatter bit-reversed + Hermitian mirror
  for (int e = tid; e < WHv * 8; e += 512) {
    int w = e >> 3, hh = e & 7;
    cplx v = F[((size_t)bc * WHv + w) * 256 + h0 + hh];
    buf[hh][brev8(w)] = v;
    if (w >= 1 && w <= 127) buf[hh][brev8(256 - w)] = make_float2(v.x, -v.y);
  }
  __syncthreads();
  fft256<1>(&buf[wv][0], tw, lane);
  __syncthreads();
  for (int e = tid; e < 8 * 256; e += 512) {
    int n = e & 255, hh = e >> 8;
    size_t o = ((size_t)bc * 256 + h0 + hh) * 256 + n;
    out[o] = buf[hh][n].x * (1.0f / 256.0f) + x[o];
  }
}

extern "C" void kernel_launch(void* const* d_in, const int* in_sizes, int n_in,
                              void* d_out, int out_size, void* d_ws, size_t ws_size,
                              hipStream_t stream) {
  const float* x  = (const float*)d_in[0];
  const float* w1 = (const float*)d_in[1];
  const float* b1 = (const float*)d_in[2];
  const float* w2 = (const float*)d_in[3];
  const float* b2 = (const float*)d_in[4];
  float* out = (float*)d_out;
  cplx* F = (cplx*)d_ws;  // (B, C, Wh, H) complex fp32 = ~406 MB
  // prepped split-bf16 weights right after F (1.18 MB, 256B-aligned offset)
  const size_t fbytes = (size_t)Bv * Cv * WHv * Hv * sizeof(cplx);
  __bf16* WP = (__bf16*)((char*)d_ws + fbytes);

  k_prep<<<2 * NBv * 3 * 6 * 4 * 64 * 8 / 256, 256, 0, stream>>>(w1, w2, WP);
  k_fwd_row<<<Bv * Cv * Hv / 8, 512, 0, stream>>>(x, F);
  k_col_fft<0><<<Bv * Cv * WHv / 8, 512, 0, stream>>>(F);
  k_mix<<<Bv * NBv * WHv * (Hv / 64), 256, 0, stream>>>(F, WP, b1, b2);
  k_col_fft<1><<<Bv * Cv * WHv / 8, 512, 0, stream>>>(F);
  k_inv_row<<<Bv * Cv * Hv / 8, 512, 0, stream>>>(F, x, out);
}

// Round 2
// 2201.306 us; speedup vs baseline: 1.3152x; 1.0788x over previous
//
#include <hip/hip_runtime.h>

#define Bv 2
#define Cv 768
#define Hv 256
#define Wv 256
#define WHv 129
#define NBv 8
#define BSv 96

typedef float2 cplx;
typedef __bf16 bf16x8 __attribute__((ext_vector_type(8)));
typedef float f32x4 __attribute__((ext_vector_type(4)));

#define MFMA(A, B, C) __builtin_amdgcn_mfma_f32_16x16x32_bf16((A), (B), (C), 0, 0, 0)

__device__ __forceinline__ unsigned brev8(unsigned v) { return __brev(v) >> 24; }

__device__ __forceinline__ cplx cmul(cplx a, cplx b) {
  return make_float2(fmaf(a.x, b.x, -a.y * b.y), fmaf(a.x, b.y, a.y * b.x));
}

// ---------------------------------------------------------------------------
// Register-resident 256-pt FFT: 4 slots/lane x 64 lanes. Forward = DIF
// (natural in -> scrambled out), inverse = mirrored DIT (scrambled in ->
// natural out). The intermediate order cancels because the spectral mixing
// is pointwise and h-uniform. No LDS, no barriers.
// ---------------------------------------------------------------------------
template <int INV>
__device__ __forceinline__ void setup_tw(int lane, cplx twA[3], cplx twS[6]) {
  float ang = -6.283185307179586f * (float)lane * (1.0f / 256.0f);
  float s0, c0;
  __sincosf(ang, &s0, &c0);
  cplx w = make_float2(c0, INV ? -s0 : s0);  // conj for inverse
  twA[0] = w;
  twA[1] = cmul(w, w);
  twA[2] = cmul(twA[1], w);
#pragma unroll
  for (int k = 0; k < 6; ++k) {
    int s = 32 >> k;
    int m = lane & (s - 1);
    float a = -6.283185307179586f * (float)m / (float)(2 * s);
    float ss, cc;
    __sincosf(a, &ss, &cc);
    if (!INV) {
      // DIF: upper lane multiplies (u-v) by w; lower passes u+v through.
      twS[k] = (lane & s) ? make_float2(cc, ss) : make_float2(1.0f, 0.0f);
    } else {
      // DIT: out = X + Y*t with t = conj(w), negated on upper lanes.
      cplx wc = make_float2(cc, -ss);
      twS[k] = (lane & s) ? make_float2(-wc.x, -wc.y) : wc;
    }
  }
}

template <int INV>
__device__ __forceinline__ void fft256_reg(cplx r[4], int lane,
                                           const cplx twA[3], const cplx twS[6]) {
  if (!INV) {
    // Stage A: radix-4 DIF across slots (n, n+64, n+128, n+192), n = lane.
    cplx a = r[0], b = r[1], c = r[2], d = r[3];
    cplx t02p = make_float2(a.x + c.x, a.y + c.y);
    cplx t02m = make_float2(a.x - c.x, a.y - c.y);
    cplx t13p = make_float2(b.x + d.x, b.y + d.y);
    cplx t13m = make_float2(b.x - d.x, b.y - d.y);
    r[0] = make_float2(t02p.x + t13p.x, t02p.y + t13p.y);
    cplx y1 = make_float2(t02m.x + t13m.y, t02m.y - t13m.x);  // (a-c) - i(b-d)
    cplx y2 = make_float2(t02p.x - t13p.x, t02p.y - t13p.y);
    cplx y3 = make_float2(t02m.x - t13m.y, t02m.y + t13m.x);  // (a-c) + i(b-d)
    r[1] = cmul(y1, twA[0]);
    r[2] = cmul(y2, twA[1]);
    r[3] = cmul(y3, twA[2]);
    // 6 cross-lane DIF radix-2 stages, strides 32..1.
#pragma unroll
    for (int k = 0; k < 6; ++k) {
      int s = 32 >> k;
      float sg = (lane & s) ? -1.0f : 1.0f;
#pragma unroll
      for (int p = 0; p < 4; ++p) {
        cplx o = r[p];
        cplx q = make_float2(__shfl_xor(o.x, s), __shfl_xor(o.y, s));
        cplx dd = make_float2(fmaf(sg, o.x, q.x), fmaf(sg, o.y, q.y));
        r[p] = cmul(dd, twS[k]);
      }
    }
  } else {
    // 6 cross-lane DIT radix-2 stages, strides 1..32 (exact mirror).
#pragma unroll
    for (int k = 5; k >= 0; --k) {
      int s = 32 >> k;
      bool up = (lane & s) != 0;
#pragma unroll
      for (int p = 0; p < 4; ++p) {
        cplx o = r[p];
        cplx q = make_float2(__shfl_xor(o.x, s), __shfl_xor(o.y, s));
        cplx X = up ? q : o;
        cplx Y = up ? o : q;
        cplx t = twS[k];
        r[p] = make_float2(fmaf(Y.x, t.x, fmaf(-Y.y, t.y, X.x)),
                           fmaf(Y.y, t.x, fmaf(Y.x, t.y, X.y)));
      }
    }
    // Stage A inverse: radix-4 DIT across slots (conj twiddles in twA).
    cplx t1 = cmul(r[1], twA[0]);
    cplx t2 = cmul(r[2], twA[1]);
    cplx t3 = cmul(r[3], twA[2]);
    cplx p02 = make_float2(r[0].x + t2.x, r[0].y + t2.y);
    cplx m02 = make_float2(r[0].x - t2.x, r[0].y - t2.y);
    cplx p13 = make_float2(t1.x + t3.x, t1.y + t3.y);
    cplx m13 = make_float2(t1.x - t3.x, t1.y - t3.y);
    r[0] = make_float2(p02.x + p13.x, p02.y + p13.y);
    r[2] = make_float2(p02.x - p13.x, p02.y - p13.y);
    r[1] = make_float2(m02.x - m13.y, m02.y + m13.x);  // + i*(t1-t3)
    r[3] = make_float2(m02.x + m13.y, m02.y - m13.x);  // - i*(t1-t3)
  }
}

// K2/K4: column FFT along H, fully in registers. 4 waves/block, 4 cols/wave.
template <int INV>
__global__ __launch_bounds__(256) void k_col_fft_r(cplx* __restrict__ F) {
  int tid = threadIdx.x;
  int lane = tid & 63, wv = tid >> 6;
  cplx twA[3], twS[6];
  setup_tw<INV>(lane, twA, twS);
  size_t col0 = ((size_t)blockIdx.x * 4 + wv) * 4;
  for (int c = 0; c < 4; ++c) {
    size_t base = (col0 + c) * 256 + lane;
    cplx r[4];
#pragma unroll
    for (int p = 0; p < 4; ++p) r[p] = F[base + 64 * p];
    fft256_reg<INV>(r, lane, twA, twS);
#pragma unroll
    for (int p = 0; p < 4; ++p) F[base + 64 * p] = r[p];
  }
}

// ---------------------------------------------------------------------------
// LDS-based 256-pt FFT (row kernels; natural order needed for mode select /
// Hermitian mirror along w).
// ---------------------------------------------------------------------------
__device__ __forceinline__ void fill_tw(cplx* tw, int lane) {
#pragma unroll
  for (int r = 0; r < 4; ++r) {
    int m = lane + (r << 6);
    float s, c;
    __sincosf((float)m * (-6.283185307179586f / 256.0f), &s, &c);
    tw[m] = make_float2(c, s);  // e^{-2*pi*i*m/256}
  }
}

template <int INV>
__device__ __forceinline__ void fft256(cplx* row, const cplx* tw, int lane) {
#pragma unroll
  for (int len = 2; len <= 256; len <<= 1) {
    const int half = len >> 1;
#pragma unroll
    for (int r = 0; r < 2; ++r) {
      int b = lane + (r << 6);      // butterfly id 0..127
      int j = b & (half - 1);
      int i0 = 2 * b - j;           // = (b/half)*len + j
      int i1 = i0 + half;
      cplx u = row[i0];
      cplx v = row[i1];
      cplx w = tw[j * (256 / len)];
      float wy = INV ? -w.y : w.y;
      float vr = v.x * w.x - v.y * wy;
      float vi = v.x * wy + v.y * w.x;
      row[i0] = make_float2(u.x + vr, u.y + vi);
      row[i1] = make_float2(u.x - vr, u.y - vi);
    }
  }
}

// K1: row rfft (real 256 -> 129 complex), write transposed F[b,c,w,h].
__global__ __launch_bounds__(512) void k_fwd_row(const float* __restrict__ x,
                                                 cplx* __restrict__ F) {
  __shared__ cplx buf[8][257];
  __shared__ cplx tw[256];
  int tid = threadIdx.x;
  int wv = tid >> 6, lane = tid & 63;
  fill_tw(tw, lane);
  int r0 = blockIdx.x * 8;
  int bc = r0 >> 8;      // image index (b*C + c)
  int h0 = r0 & 255;     // first row in this block
  const float* xr = x + ((size_t)bc * 256 + (size_t)(h0 + wv)) * 256;
#pragma unroll
  for (int r = 0; r < 4; ++r) {
    int idx = lane + (r << 6);
    buf[wv][brev8(idx)] = make_float2(xr[idx], 0.0f);
  }
  fft256<0>(&buf[wv][0], tw, lane);
  __syncthreads();  // cross-wave transposed write below
  for (int e = tid; e < WHv * 8; e += 512) {
    int w = e >> 3, hh = e & 7;
    F[((size_t)bc * WHv + w) * 256 + h0 + hh] = buf[hh][w];
  }
}

// Prep: split w1/w2 into hi/lo bf16 and swizzle into MFMA A-fragment order.
// Layout: [L][k][ks][m][term(rH,rL,iH,iL)][lane][j]  (j = 8 contiguous K elems)
// value = W[k][i][o] with i = ks*32 + (lane>>4)*8 + j, o = m*16 + (lane&15).
// Forward ortho scale 1/256 folded into W1.
__global__ __launch_bounds__(256) void k_prep(const float* __restrict__ w1,
                                              const float* __restrict__ w2,
                                              __bf16* __restrict__ wp) {
  int idx = blockIdx.x * 256 + threadIdx.x;
  int j = idx & 7;
  int lane = (idx >> 3) & 63;
  int term = (idx >> 9) & 3;
  int t2 = idx >> 11;
  int m = t2 % 6; t2 /= 6;
  int ks = t2 % 3; t2 /= 3;
  int k = t2 & 7;
  int L = t2 >> 3;
  int i = ks * 32 + ((lane >> 4) << 3) + j;
  int o = (m << 4) + (lane & 15);
  const float* src = L ? w2 : w1;
  float v = src[(((size_t)k * BSv + i) * BSv + o) * 2 + (term >> 1)];
  if (L == 0) v *= (1.0f / 256.0f);
  __bf16 h = (__bf16)v;
  __bf16 r = (term & 1) ? (__bf16)(v - (float)h) : h;
  wp[idx] = r;
}

// One layer of the complex MLP: acc = W^T * A over K=96, split-bf16 MFMA.
__device__ __forceinline__ void mlp_layer(const cplx (*T)[65],
                                          const bf16x8* __restrict__ q0,
                                          int lane, int lg, int hcol,
                                          f32x4 accr[6], f32x4 acci[6]) {
#pragma unroll
  for (int m = 0; m < 6; ++m) {
    accr[m] = (f32x4){0.0f, 0.0f, 0.0f, 0.0f};
    acci[m] = (f32x4){0.0f, 0.0f, 0.0f, 0.0f};
  }
#pragma unroll
  for (int ks = 0; ks < 3; ++ks) {
    bf16x8 arh, arl, aih, ail, aihn, ailn;
    int i0 = ks * 32 + (lg << 3);
#pragma unroll
    for (int j = 0; j < 8; ++j) {
      cplx a = T[i0 + j][hcol];
      __bf16 rh = (__bf16)a.x;
      float rhf = (float)rh;
      __bf16 rl = (__bf16)(a.x - rhf);
      __bf16 ih = (__bf16)a.y;
      float ihf = (float)ih;
      __bf16 il = (__bf16)(a.y - ihf);
      arh[j] = rh;  arl[j] = rl;
      aih[j] = ih;  ail[j] = il;
      aihn[j] = (__bf16)(0.0f - ihf);      // exact negation of hi
      ailn[j] = (__bf16)(ihf - a.y);       // exact negation of lo
    }
    const bf16x8* q = q0 + ks * (6 * 4 * 64) + lane;
#pragma unroll
    for (int m = 0; m < 6; ++m) {
      bf16x8 wrh = q[(m * 4 + 0) * 64];
      bf16x8 wrl = q[(m * 4 + 1) * 64];
      bf16x8 wih = q[(m * 4 + 2) * 64];
      bf16x8 wil = q[(m * 4 + 3) * 64];
      f32x4 ar = accr[m], ai = acci[m];
      // Or = Wr*Ar - Wi*Ai   (3-term split each)
      ar = MFMA(wrh, arh, ar);
      ar = MFMA(wrh, arl, ar);
      ar = MFMA(wrl, arh, ar);
      ar = MFMA(wih, aihn, ar);
      ar = MFMA(wih, ailn, ar);
      ar = MFMA(wil, aihn, ar);
      // Oi = Wr*Ai + Wi*Ar
      ai = MFMA(wrh, aih, ai);
      ai = MFMA(wrh, ail, ai);
      ai = MFMA(wrl, aih, ai);
      ai = MFMA(wih, arh, ai);
      ai = MFMA(wih, arl, ai);
      ai = MFMA(wil, arh, ai);
      accr[m] = ar;
      acci[m] = ai;
    }
  }
}

// K3: per-mode block-diagonal complex MLP via split-bf16 MFMA, in place on F.
__global__ __launch_bounds__(256) void k_mix(cplx* __restrict__ F,
                                             const __bf16* __restrict__ WPg,
                                             const float* __restrict__ b1,
                                             const float* __restrict__ b2) {
  __shared__ cplx T[BSv][65];  // 49920 B
  int bid = blockIdx.x;
  int ht = bid & 3; bid >>= 2;
  int w = bid % WHv; bid /= WHv;
  int k = bid & 7;
  int b = bid >> 3;
  int tid = threadIdx.x;
  int lane = tid & 63;
  int wv = __builtin_amdgcn_readfirstlane(tid >> 6);
  int lg = lane >> 4;
  int hcol = (wv << 4) + (lane & 15);
  int h0 = ht << 6;
  size_t base = ((size_t)(b * Cv + k * BSv) * WHv + w) * 256 + h0;
  const size_t cstride = (size_t)WHv * 256;

  // Stage A tile (96 channels x 64 h). 1/256 ortho scale is folded into W1.
  for (int e = tid; e < BSv * 64; e += 256) {
    int i = e >> 6, hh = e & 63;
    T[i][hh] = F[base + (size_t)i * cstride + hh];
  }
  __syncthreads();

  const bf16x8* WPv = (const bf16x8*)WPg;
  f32x4 accr[6], acci[6];

  // ---- layer 1 ----
  mlp_layer(T, WPv + (size_t)k * (3 * 6 * 4 * 64), lane, lg, hcol, accr, acci);
  __syncthreads();  // all waves done reading A tile

  // bias + relu -> o1 back into T  (D layout: o = m*16 + lg*4 + r, col = hcol)
  const cplx* B1 = (const cplx*)b1 + k * BSv;
#pragma unroll
  for (int m = 0; m < 6; ++m) {
#pragma unroll
    for (int r = 0; r < 4; ++r) {
      int o = (m << 4) + (lg << 2) + r;
      cplx bb = B1[o];
      T[o][hcol] = make_float2(fmaxf(accr[m][r] + bb.x, 0.0f),
                               fmaxf(acci[m][r] + bb.y, 0.0f));
    }
  }
  __syncthreads();  // o1 visible to all

  // ---- layer 2 ----
  mlp_layer(T, WPv + (size_t)(8 + k) * (3 * 6 * 4 * 64), lane, lg, hcol, accr, acci);

  const cplx* B2 = (const cplx*)b2 + k * BSv;
#pragma unroll
  for (int m = 0; m < 6; ++m) {
#pragma unroll
    for (int r = 0; r < 4; ++r) {
      int o = (m << 4) + (lg << 2) + r;
      cplx bb = B2[o];
      float re = accr[m][r] + bb.x;
      float im = acci[m][r] + bb.y;
      re = copysignf(fmaxf(fabsf(re) - 0.01f, 0.0f), re);  // softshrink
      im = copysignf(fmaxf(fabsf(im) - 0.01f, 0.0f), im);
      F[base + (size_t)o * cstride + hcol] = make_float2(re, im);
    }
  }
}

// K5: Hermitian-extend along w, inverse FFT, real part * 1/256 + residual.
__global__ __launch_bounds__(512) void k_inv_row(const cplx* __restrict__ F,
                                                 const float* __restrict__ x,
                                                 float* __restrict__ out) {
  __shared__ cplx buf[8][257];
  __shared__ cplx tw[256];
  int tid = threadIdx.x;
  int wv = tid >> 6, lane = tid & 63;
  fill_tw(tw, lane);
  int r0 = blockIdx.x * 8;
  int bc = r0 >> 8;
  int h0 = r0 & 255;
  // gather spectrum tile [129 w][8 h], scatter bit-reversed + Hermitian mirror
  for (int e = tid; e < WHv * 8; e += 512) {
    int w = e >> 3, hh = e & 7;
    cplx v = F[((size_t)bc * WHv + w) * 256 + h0 + hh];
    buf[hh][brev8(w)] = v;
    if (w >= 1 && w <= 127) buf[hh][brev8(256 - w)] = make_float2(v.x, -v.y);
  }
  __syncthreads();
  fft256<1>(&buf[wv][0], tw, lane);
  __syncthreads();
  for (int e = tid; e < 8 * 256; e += 512) {
    int n = e & 255, hh = e >> 8;
    size_t o = ((size_t)bc * 256 + h0 + hh) * 256 + n;
    out[o] = buf[hh][n].x * (1.0f / 256.0f) + x[o];
  }
}

extern "C" void kernel_launch(void* const* d_in, const int* in_sizes, int n_in,
                              void* d_out, int out_size, void* d_ws, size_t ws_size,
                              hipStream_t stream) {
  const float* x  = (const float*)d_in[0];
  const float* w1 = (const float*)d_in[1];
  const float* b1 = (const float*)d_in[2];
  const float* w2 = (const float*)d_in[3];
  const float* b2 = (const float*)d_in[4];
  float* out = (float*)d_out;
  cplx* F = (cplx*)d_ws;  // (B, C, Wh, H) complex fp32 = ~406 MB
  const size_t fbytes = (size_t)Bv * Cv * WHv * Hv * sizeof(cplx);
  __bf16* WP = (__bf16*)((char*)d_ws + fbytes);

  k_prep<<<2 * NBv * 3 * 6 * 4 * 64 * 8 / 256, 256, 0, stream>>>(w1, w2, WP);
  k_fwd_row<<<Bv * Cv * Hv / 8, 512, 0, stream>>>(x, F);
  k_col_fft_r<0><<<Bv * Cv * WHv / 16, 256, 0, stream>>>(F);
  k_mix<<<Bv * NBv * WHv * (Hv / 64), 256, 0, stream>>>(F, WP, b1, b2);
  k_col_fft_r<1><<<Bv * Cv * WHv / 16, 256, 0, stream>>>(F);
  k_inv_row<<<Bv * Cv * Hv / 8, 512, 0, stream>>>(F, x, out);
}

// Round 3
// 1966.822 us; speedup vs baseline: 1.4720x; 1.1192x over previous
//
#include <hip/hip_runtime.h>

#define Bv 2
#define Cv 768
#define Hv 256
#define Wv 256
#define WHv 129
#define NBv 8
#define BSv 96

typedef float2 cplx;
typedef __bf16 bf16x8 __attribute__((ext_vector_type(8)));
typedef float f32x4 __attribute__((ext_vector_type(4)));

#define MFMA(A, B, C) __builtin_amdgcn_mfma_f32_16x16x32_bf16((A), (B), (C), 0, 0, 0)

__device__ __forceinline__ unsigned brev8(unsigned v) { return __brev(v) >> 24; }

__device__ __forceinline__ cplx cmul(cplx a, cplx b) {
  return make_float2(fmaf(a.x, b.x, -a.y * b.y), fmaf(a.x, b.y, a.y * b.x));
}

// ---------------------------------------------------------------------------
// Register-resident 256-pt FFT: 4 slots/lane x 64 lanes. Forward = DIF
// (natural in -> scrambled out), inverse = mirrored DIT (scrambled in ->
// natural out). Scramble cancels because spectral mixing is h-uniform.
// ---------------------------------------------------------------------------
template <int INV>
__device__ __forceinline__ void setup_tw(int lane, cplx twA[3], cplx twS[6]) {
  float ang = -6.283185307179586f * (float)lane * (1.0f / 256.0f);
  float s0, c0;
  __sincosf(ang, &s0, &c0);
  cplx w = make_float2(c0, INV ? -s0 : s0);  // conj for inverse
  twA[0] = w;
  twA[1] = cmul(w, w);
  twA[2] = cmul(twA[1], w);
#pragma unroll
  for (int k = 0; k < 6; ++k) {
    int s = 32 >> k;
    int m = lane & (s - 1);
    float a = -6.283185307179586f * (float)m / (float)(2 * s);
    float ss, cc;
    __sincosf(a, &ss, &cc);
    if (!INV) {
      twS[k] = (lane & s) ? make_float2(cc, ss) : make_float2(1.0f, 0.0f);
    } else {
      cplx wc = make_float2(cc, -ss);
      twS[k] = (lane & s) ? make_float2(-wc.x, -wc.y) : wc;
    }
  }
}

template <int INV>
__device__ __forceinline__ void fft256_reg(cplx r[4], int lane,
                                           const cplx twA[3], const cplx twS[6]) {
  if (!INV) {
    cplx a = r[0], b = r[1], c = r[2], d = r[3];
    cplx t02p = make_float2(a.x + c.x, a.y + c.y);
    cplx t02m = make_float2(a.x - c.x, a.y - c.y);
    cplx t13p = make_float2(b.x + d.x, b.y + d.y);
    cplx t13m = make_float2(b.x - d.x, b.y - d.y);
    r[0] = make_float2(t02p.x + t13p.x, t02p.y + t13p.y);
    cplx y1 = make_float2(t02m.x + t13m.y, t02m.y - t13m.x);
    cplx y2 = make_float2(t02p.x - t13p.x, t02p.y - t13p.y);
    cplx y3 = make_float2(t02m.x - t13m.y, t02m.y + t13m.x);
    r[1] = cmul(y1, twA[0]);
    r[2] = cmul(y2, twA[1]);
    r[3] = cmul(y3, twA[2]);
#pragma unroll
    for (int k = 0; k < 6; ++k) {
      int s = 32 >> k;
      float sg = (lane & s) ? -1.0f : 1.0f;
#pragma unroll
      for (int p = 0; p < 4; ++p) {
        cplx o = r[p];
        cplx q = make_float2(__shfl_xor(o.x, s), __shfl_xor(o.y, s));
        cplx dd = make_float2(fmaf(sg, o.x, q.x), fmaf(sg, o.y, q.y));
        r[p] = cmul(dd, twS[k]);
      }
    }
  } else {
#pragma unroll
    for (int k = 5; k >= 0; --k) {
      int s = 32 >> k;
      bool up = (lane & s) != 0;
#pragma unroll
      for (int p = 0; p < 4; ++p) {
        cplx o = r[p];
        cplx q = make_float2(__shfl_xor(o.x, s), __shfl_xor(o.y, s));
        cplx X = up ? q : o;
        cplx Y = up ? o : q;
        cplx t = twS[k];
        r[p] = make_float2(fmaf(Y.x, t.x, fmaf(-Y.y, t.y, X.x)),
                           fmaf(Y.y, t.x, fmaf(Y.x, t.y, X.y)));
      }
    }
    cplx t1 = cmul(r[1], twA[0]);
    cplx t2 = cmul(r[2], twA[1]);
    cplx t3 = cmul(r[3], twA[2]);
    cplx p02 = make_float2(r[0].x + t2.x, r[0].y + t2.y);
    cplx m02 = make_float2(r[0].x - t2.x, r[0].y - t2.y);
    cplx p13 = make_float2(t1.x + t3.x, t1.y + t3.y);
    cplx m13 = make_float2(t1.x - t3.x, t1.y - t3.y);
    r[0] = make_float2(p02.x + p13.x, p02.y + p13.y);
    r[2] = make_float2(p02.x - p13.x, p02.y - p13.y);
    r[1] = make_float2(m02.x - m13.y, m02.y + m13.x);
    r[3] = make_float2(m02.x + m13.y, m02.y - m13.x);
  }
}

// K2/K4: column FFT along H, fully in registers. 4 waves/block, 4 cols/wave.
template <int INV>
__global__ __launch_bounds__(256) void k_col_fft_r(cplx* __restrict__ F) {
  int tid = threadIdx.x;
  int lane = tid & 63, wv = tid >> 6;
  cplx twA[3], twS[6];
  setup_tw<INV>(lane, twA, twS);
  size_t col0 = ((size_t)blockIdx.x * 4 + wv) * 4;
  for (int c = 0; c < 4; ++c) {
    size_t base = (col0 + c) * 256 + lane;
    cplx r[4];
#pragma unroll
    for (int p = 0; p < 4; ++p) r[p] = F[base + 64 * p];
    fft256_reg<INV>(r, lane, twA, twS);
#pragma unroll
    for (int p = 0; p < 4; ++p) F[base + 64 * p] = r[p];
  }
}

// ---------------------------------------------------------------------------
// LDS-based 256-pt FFT (row kernels; natural order needed along w).
// ---------------------------------------------------------------------------
__device__ __forceinline__ void fill_tw(cplx* tw, int lane) {
#pragma unroll
  for (int r = 0; r < 4; ++r) {
    int m = lane + (r << 6);
    float s, c;
    __sincosf((float)m * (-6.283185307179586f / 256.0f), &s, &c);
    tw[m] = make_float2(c, s);
  }
}

template <int INV>
__device__ __forceinline__ void fft256(cplx* row, const cplx* tw, int lane) {
#pragma unroll
  for (int len = 2; len <= 256; len <<= 1) {
    const int half = len >> 1;
#pragma unroll
    for (int r = 0; r < 2; ++r) {
      int b = lane + (r << 6);
      int j = b & (half - 1);
      int i0 = 2 * b - j;
      int i1 = i0 + half;
      cplx u = row[i0];
      cplx v = row[i1];
      cplx w = tw[j * (256 / len)];
      float wy = INV ? -w.y : w.y;
      float vr = v.x * w.x - v.y * wy;
      float vi = v.x * wy + v.y * w.x;
      row[i0] = make_float2(u.x + vr, u.y + vi);
      row[i1] = make_float2(u.x - vr, u.y - vi);
    }
  }
}

// K1: row rfft (real 256 -> 129 complex), write transposed F[b,c,w,h].
__global__ __launch_bounds__(512) void k_fwd_row(const float* __restrict__ x,
                                                 cplx* __restrict__ F) {
  __shared__ cplx buf[8][257];
  __shared__ cplx tw[256];
  int tid = threadIdx.x;
  int wv = tid >> 6, lane = tid & 63;
  fill_tw(tw, lane);
  int r0 = blockIdx.x * 8;
  int bc = r0 >> 8;
  int h0 = r0 & 255;
  const float* xr = x + ((size_t)bc * 256 + (size_t)(h0 + wv)) * 256;
#pragma unroll
  for (int r = 0; r < 4; ++r) {
    int idx = lane + (r << 6);
    buf[wv][brev8(idx)] = make_float2(xr[idx], 0.0f);
  }
  fft256<0>(&buf[wv][0], tw, lane);
  __syncthreads();
  for (int e = tid; e < WHv * 8; e += 512) {
    int w = e >> 3, hh = e & 7;
    F[((size_t)bc * WHv + w) * 256 + h0 + hh] = buf[hh][w];
  }
}

// Prep: split w1/w2 into hi/lo bf16 and swizzle into MFMA A-fragment order.
// Layout: [L][k][ks][m][term(rH,rL,iH,iL)][lane][j]  (j = 8 K-slot elems)
//   L=0 (w1): K-slot s = (lane>>4)*8+j  ->  i = ks*32 + s   (natural)
//   L=1 (w2): K-slot s carries o1-row sigma(s) so that layer-2 B-frags are
//             the layer-1 D-frags in-lane:
//             i = ks*32 + (j>>2)*16 + ((lane>>4)<<2) + (j&3)
// value = W[k][i][o] with o = m*16 + (lane&15). 1/256 folded into W1.
__global__ __launch_bounds__(256) void k_prep(const float* __restrict__ w1,
                                              const float* __restrict__ w2,
                                              __bf16* __restrict__ wp) {
  int idx = blockIdx.x * 256 + threadIdx.x;
  int j = idx & 7;
  int lane = (idx >> 3) & 63;
  int term = (idx >> 9) & 3;
  int t2 = idx >> 11;
  int m = t2 % 6; t2 /= 6;
  int ks = t2 % 3; t2 /= 3;
  int k = t2 & 7;
  int L = t2 >> 3;
  int i;
  if (L == 0) {
    i = ks * 32 + ((lane >> 4) << 3) + j;
  } else {
    i = ks * 32 + ((j >> 2) << 4) + ((lane >> 4) << 2) + (j & 3);
  }
  int o = (m << 4) + (lane & 15);
  const float* src = L ? w2 : w1;
  float v = src[(((size_t)k * BSv + i) * BSv + o) * 2 + (term >> 1)];
  if (L == 0) v *= (1.0f / 256.0f);
  __bf16 h = (__bf16)v;
  __bf16 r = (term & 1) ? (__bf16)(v - (float)h) : h;
  wp[idx] = r;
}

// Build the six split-bf16 fragment arrays from a complex value.
__device__ __forceinline__ void split6(float re, float im, int j,
                                       bf16x8& rh, bf16x8& rl,
                                       bf16x8& ih, bf16x8& il,
                                       bf16x8& ihn, bf16x8& iln) {
  __bf16 h = (__bf16)re;
  float hf = (float)h;
  rh[j] = h;
  rl[j] = (__bf16)(re - hf);
  __bf16 g = (__bf16)im;
  float gf = (float)g;
  ih[j] = g;
  il[j] = (__bf16)(im - gf);
  ihn[j] = (__bf16)(0.0f - gf);
  iln[j] = (__bf16)(gf - im);
}

__device__ __forceinline__ void mfma12(const bf16x8* q, int m,
                                       const bf16x8& rh, const bf16x8& rl,
                                       const bf16x8& ih, const bf16x8& il,
                                       const bf16x8& ihn, const bf16x8& iln,
                                       f32x4& ar, f32x4& ai) {
  bf16x8 wrh = q[(m * 4 + 0) * 64];
  bf16x8 wrl = q[(m * 4 + 1) * 64];
  bf16x8 wih = q[(m * 4 + 2) * 64];
  bf16x8 wil = q[(m * 4 + 3) * 64];
  // Or = Wr*Ar - Wi*Ai (3-term split each)
  ar = MFMA(wrh, rh, ar);
  ar = MFMA(wrh, rl, ar);
  ar = MFMA(wrl, rh, ar);
  ar = MFMA(wih, ihn, ar);
  ar = MFMA(wih, iln, ar);
  ar = MFMA(wil, ihn, ar);
  // Oi = Wr*Ai + Wi*Ar
  ai = MFMA(wrh, ih, ai);
  ai = MFMA(wrh, il, ai);
  ai = MFMA(wrl, ih, ai);
  ai = MFMA(wih, rh, ai);
  ai = MFMA(wih, rl, ai);
  ai = MFMA(wil, rh, ai);
}

// K3: per-mode block-diagonal complex MLP. One fully-independent wave per
// (b, k, w, 16-h slice): no LDS, no barriers. Layer-1 B-frags straight from
// global (128B-line coalesced); layer-2 B-frags are layer-1 D-frags in-lane
// (sigma baked into k_prep's L=1 weight layout).
__global__ __launch_bounds__(256) void k_mix(cplx* __restrict__ F,
                                             const __bf16* __restrict__ WPg,
                                             const float* __restrict__ b1,
                                             const float* __restrict__ b2) {
  int tid = threadIdx.x;
  int lane = tid & 63;
  int gw = blockIdx.x * 4 + (tid >> 6);  // global wave id
  int ht = gw & 15; gw >>= 4;            // 16-h slice
  int w = gw % WHv; gw /= WHv;
  int k = gw & 7;
  int b = gw >> 3;
  int lg = lane >> 4;
  int hc = lane & 15;
  const size_t cstride = (size_t)WHv * 256;
  size_t base = ((size_t)(b * Cv + k * BSv) * WHv + w) * 256 + (ht << 4) + hc;

  const bf16x8* WPv = (const bf16x8*)WPg;
  const bf16x8* q1 = WPv + (size_t)k * (3 * 6 * 4 * 64) + lane;
  const bf16x8* q2 = WPv + (size_t)(8 + k) * (3 * 6 * 4 * 64) + lane;

  f32x4 acr[6], aci[6];
#pragma unroll
  for (int m = 0; m < 6; ++m) {
    acr[m] = (f32x4){0.0f, 0.0f, 0.0f, 0.0f};
    aci[m] = (f32x4){0.0f, 0.0f, 0.0f, 0.0f};
  }

  // ---- layer 1 ----
#pragma unroll
  for (int ks = 0; ks < 3; ++ks) {
    bf16x8 rh, rl, ih, il, ihn, iln;
#pragma unroll
    for (int j = 0; j < 8; ++j) {
      cplx a = F[base + (size_t)(ks * 32 + (lg << 3) + j) * cstride];
      split6(a.x, a.y, j, rh, rl, ih, il, ihn, iln);
    }
    const bf16x8* q = q1 + ks * (6 * 4 * 64);
#pragma unroll
    for (int m = 0; m < 6; ++m)
      mfma12(q, m, rh, rl, ih, il, ihn, iln, acr[m], aci[m]);
  }

  // bias + relu in-register (D layout: row o = m*16 + lg*4 + r, col hc)
  const cplx* B1 = (const cplx*)b1 + k * BSv;
#pragma unroll
  for (int m = 0; m < 6; ++m) {
#pragma unroll
    for (int r = 0; r < 4; ++r) {
      cplx bb = B1[(m << 4) + (lg << 2) + r];
      acr[m][r] = fmaxf(acr[m][r] + bb.x, 0.0f);
      aci[m][r] = fmaxf(aci[m][r] + bb.y, 0.0f);
    }
  }

  // ---- layer 2 ----  (B-frag[j] = acc[2ks + (j>>2)][j&3], same lane)
  f32x4 dcr[6], dci[6];
#pragma unroll
  for (int m = 0; m < 6; ++m) {
    dcr[m] = (f32x4){0.0f, 0.0f, 0.0f, 0.0f};
    dci[m] = (f32x4){0.0f, 0.0f, 0.0f, 0.0f};
  }
#pragma unroll
  for (int ks = 0; ks < 3; ++ks) {
    bf16x8 rh, rl, ih, il, ihn, iln;
#pragma unroll
    for (int j = 0; j < 8; ++j) {
      int mt = 2 * ks + (j >> 2);
      float re = acr[mt][j & 3];
      float im = aci[mt][j & 3];
      split6(re, im, j, rh, rl, ih, il, ihn, iln);
    }
    const bf16x8* q = q2 + ks * (6 * 4 * 64);
#pragma unroll
    for (int m = 0; m < 6; ++m)
      mfma12(q, m, rh, rl, ih, il, ihn, iln, dcr[m], dci[m]);
  }

  // bias + softshrink + store (same D layout)
  const cplx* B2 = (const cplx*)b2 + k * BSv;
#pragma unroll
  for (int m = 0; m < 6; ++m) {
#pragma unroll
    for (int r = 0; r < 4; ++r) {
      int o = (m << 4) + (lg << 2) + r;
      cplx bb = B2[o];
      float re = dcr[m][r] + bb.x;
      float im = dci[m][r] + bb.y;
      re = copysignf(fmaxf(fabsf(re) - 0.01f, 0.0f), re);
      im = copysignf(fmaxf(fabsf(im) - 0.01f, 0.0f), im);
      F[base + (size_t)o * cstride] = make_float2(re, im);
    }
  }
}

// K5: Hermitian-extend along w, inverse FFT, real part * 1/256 + residual.
__global__ __launch_bounds__(512) void k_inv_row(const cplx* __restrict__ F,
                                                 const float* __restrict__ x,
                                                 float* __restrict__ out) {
  __shared__ cplx buf[8][257];
  __shared__ cplx tw[256];
  int tid = threadIdx.x;
  int wv = tid >> 6, lane = tid & 63;
  fill_tw(tw, lane);
  int r0 = blockIdx.x * 8;
  int bc = r0 >> 8;
  int h0 = r0 & 255;
  for (int e = tid; e < WHv * 8; e += 512) {
    int w = e >> 3, hh = e & 7;
    cplx v = F[((size_t)bc * WHv + w) * 256 + h0 + hh];
    buf[hh][brev8(w)] = v;
    if (w >= 1 && w <= 127) buf[hh][brev8(256 - w)] = make_float2(v.x, -v.y);
  }
  __syncthreads();
  fft256<1>(&buf[wv][0], tw, lane);
  __syncthreads();
  for (int e = tid; e < 8 * 256; e += 512) {
    int n = e & 255, hh = e >> 8;
    size_t o = ((size_t)bc * 256 + h0 + hh) * 256 + n;
    out[o] = buf[hh][n].x * (1.0f / 256.0f) + x[o];
  }
}

extern "C" void kernel_launch(void* const* d_in, const int* in_sizes, int n_in,
                              void* d_out, int out_size, void* d_ws, size_t ws_size,
                              hipStream_t stream) {
  const float* x  = (const float*)d_in[0];
  const float* w1 = (const float*)d_in[1];
  const float* b1 = (const float*)d_in[2];
  const float* w2 = (const float*)d_in[3];
  const float* b2 = (const float*)d_in[4];
  float* out = (float*)d_out;
  cplx* F = (cplx*)d_ws;  // (B, C, Wh, H) complex fp32 = ~406 MB
  const size_t fbytes = (size_t)Bv * Cv * WHv * Hv * sizeof(cplx);
  __bf16* WP = (__bf16*)((char*)d_ws + fbytes);

  k_prep<<<2 * NBv * 3 * 6 * 4 * 64 * 8 / 256, 256, 0, stream>>>(w1, w2, WP);
  k_fwd_row<<<Bv * Cv * Hv / 8, 512, 0, stream>>>(x, F);
  k_col_fft_r<0><<<Bv * Cv * WHv / 16, 256, 0, stream>>>(F);
  // one independent wave per (b,k,w,16h): 2*8*129*16 waves / 4 per block
  k_mix<<<Bv * NBv * WHv * 16 / 4, 256, 0, stream>>>(F, WP, b1, b2);
  k_col_fft_r<1><<<Bv * Cv * WHv / 16, 256, 0, stream>>>(F);
  k_inv_row<<<Bv * Cv * Hv / 8, 512, 0, stream>>>(F, x, out);
}

// Round 4
// 1510.297 us; speedup vs baseline: 1.9170x; 1.3023x over previous
//
#include <hip/hip_runtime.h>

#define Bv 2
#define Cv 768
#define Hv 256
#define Wv 256
#define WHv 129
#define NBv 8
#define BSv 96

typedef float2 cplx;
typedef __bf16 bf16x8 __attribute__((ext_vector_type(8)));
typedef float f32x4 __attribute__((ext_vector_type(4)));

#define MFMA(A, B, C) __builtin_amdgcn_mfma_f32_16x16x32_bf16((A), (B), (C), 0, 0, 0)

__device__ __forceinline__ int brev6(int v) { return (int)(__brev((unsigned)v) >> 26); }

__device__ __forceinline__ cplx cmul(cplx a, cplx b) {
  return make_float2(fmaf(a.x, b.x, -a.y * b.y), fmaf(a.x, b.y, a.y * b.x));
}

// ---------------------------------------------------------------------------
// Register-resident 256-pt FFT: 4 slots/lane x 64 lanes.
// Forward = DIF, natural in -> scrambled out: value (slot q, lane l) holds
// frequency f = 4*brev6(l) + q. Inverse = mirrored DIT, scrambled in (same
// convention) -> natural out. No LDS, no barriers.
// ---------------------------------------------------------------------------
template <int INV>
__device__ __forceinline__ void setup_tw(int lane, cplx twA[3], cplx twS[6]) {
  float ang = -6.283185307179586f * (float)lane * (1.0f / 256.0f);
  float s0, c0;
  __sincosf(ang, &s0, &c0);
  cplx w = make_float2(c0, INV ? -s0 : s0);  // conj for inverse
  twA[0] = w;
  twA[1] = cmul(w, w);
  twA[2] = cmul(twA[1], w);
#pragma unroll
  for (int k = 0; k < 6; ++k) {
    int s = 32 >> k;
    int m = lane & (s - 1);
    float a = -6.283185307179586f * (float)m / (float)(2 * s);
    float ss, cc;
    __sincosf(a, &ss, &cc);
    if (!INV) {
      twS[k] = (lane & s) ? make_float2(cc, ss) : make_float2(1.0f, 0.0f);
    } else {
      cplx wc = make_float2(cc, -ss);
      twS[k] = (lane & s) ? make_float2(-wc.x, -wc.y) : wc;
    }
  }
}

template <int INV>
__device__ __forceinline__ void fft256_reg(cplx r[4], int lane,
                                           const cplx twA[3], const cplx twS[6]) {
  if (!INV) {
    cplx a = r[0], b = r[1], c = r[2], d = r[3];
    cplx t02p = make_float2(a.x + c.x, a.y + c.y);
    cplx t02m = make_float2(a.x - c.x, a.y - c.y);
    cplx t13p = make_float2(b.x + d.x, b.y + d.y);
    cplx t13m = make_float2(b.x - d.x, b.y - d.y);
    r[0] = make_float2(t02p.x + t13p.x, t02p.y + t13p.y);
    cplx y1 = make_float2(t02m.x + t13m.y, t02m.y - t13m.x);
    cplx y2 = make_float2(t02p.x - t13p.x, t02p.y - t13p.y);
    cplx y3 = make_float2(t02m.x - t13m.y, t02m.y + t13m.x);
    r[1] = cmul(y1, twA[0]);
    r[2] = cmul(y2, twA[1]);
    r[3] = cmul(y3, twA[2]);
#pragma unroll
    for (int k = 0; k < 6; ++k) {
      int s = 32 >> k;
      float sg = (lane & s) ? -1.0f : 1.0f;
#pragma unroll
      for (int p = 0; p < 4; ++p) {
        cplx o = r[p];
        cplx q = make_float2(__shfl_xor(o.x, s), __shfl_xor(o.y, s));
        cplx dd = make_float2(fmaf(sg, o.x, q.x), fmaf(sg, o.y, q.y));
        r[p] = cmul(dd, twS[k]);
      }
    }
  } else {
#pragma unroll
    for (int k = 5; k >= 0; --k) {
      int s = 32 >> k;
      bool up = (lane & s) != 0;
#pragma unroll
      for (int p = 0; p < 4; ++p) {
        cplx o = r[p];
        cplx q = make_float2(__shfl_xor(o.x, s), __shfl_xor(o.y, s));
        cplx X = up ? q : o;
        cplx Y = up ? o : q;
        cplx t = twS[k];
        r[p] = make_float2(fmaf(Y.x, t.x, fmaf(-Y.y, t.y, X.x)),
                           fmaf(Y.y, t.x, fmaf(Y.x, t.y, X.y)));
      }
    }
    cplx t1 = cmul(r[1], twA[0]);
    cplx t2 = cmul(r[2], twA[1]);
    cplx t3 = cmul(r[3], twA[2]);
    cplx p02 = make_float2(r[0].x + t2.x, r[0].y + t2.y);
    cplx m02 = make_float2(r[0].x - t2.x, r[0].y - t2.y);
    cplx p13 = make_float2(t1.x + t3.x, t1.y + t3.y);
    cplx m13 = make_float2(t1.x - t3.x, t1.y - t3.y);
    r[0] = make_float2(p02.x + p13.x, p02.y + p13.y);
    r[2] = make_float2(p02.x - p13.x, p02.y - p13.y);
    r[1] = make_float2(m02.x - m13.y, m02.y + m13.x);
    r[3] = make_float2(m02.x + m13.y, m02.y - m13.x);
  }
}

// K2/K4: column FFT along H, fully in registers. 4 waves/block, 4 cols/wave.
template <int INV>
__global__ __launch_bounds__(256) void k_col_fft_r(cplx* __restrict__ F) {
  int tid = threadIdx.x;
  int lane = tid & 63, wv = tid >> 6;
  cplx twA[3], twS[6];
  setup_tw<INV>(lane, twA, twS);
  size_t col0 = ((size_t)blockIdx.x * 4 + wv) * 4;
  for (int c = 0; c < 4; ++c) {
    size_t base = (col0 + c) * 256 + lane;
    cplx r[4];
#pragma unroll
    for (int p = 0; p < 4; ++p) r[p] = F[base + 64 * p];
    fft256_reg<INV>(r, lane, twA, twS);
#pragma unroll
    for (int p = 0; p < 4; ++p) F[base + 64 * p] = r[p];
  }
}

// Swizzled LDS column for natural index f (bijection; bank-spreads both the
// scrambled fragment access and the natural-order access).
__device__ __forceinline__ int swz(int f) { return f ^ (f >> 4); }

// K1: row rfft, 2 real rows packed per wave. 512 thr = 8 waves = 16 h-rows.
// Register DIF -> swizzled LDS (natural order) -> Hermitian unpack +
// transposed store F[b,c,w,h].
__global__ __launch_bounds__(512) void k_fwd_row(const float* __restrict__ x,
                                                 cplx* __restrict__ F) {
  __shared__ cplx buf[8][258];
  int tid = threadIdx.x;
  int lane = tid & 63, wv = tid >> 6;
  cplx twA[3], twS[6];
  setup_tw<0>(lane, twA, twS);
  int bc = blockIdx.x >> 4;
  int h0 = (blockIdx.x & 15) << 4;
  const float* x1 = x + ((size_t)bc * 256 + h0 + 2 * wv) * 256;
  const float* x2 = x1 + 256;
  cplx r[4];
#pragma unroll
  for (int p = 0; p < 4; ++p) {
    int n = (p << 6) + lane;
    r[p] = make_float2(x1[n], x2[n]);  // z = x_h + i*x_{h+1}
  }
  fft256_reg<0>(r, lane, twA, twS);
  int f0 = brev6(lane) << 2;
#pragma unroll
  for (int q = 0; q < 4; ++q) buf[wv][(f0 + q) ^ (f0 >> 4)] = r[q];
  __syncthreads();
  for (int e = tid; e < WHv * 16; e += 512) {
    int w = e >> 4, hh = e & 15;
    int p = hh >> 1;
    int wm = (256 - w) & 255;
    cplx Z = buf[p][swz(w)];
    cplx Zc = buf[p][swz(wm)];
    cplx X;
    if (!(hh & 1))
      X = make_float2(0.5f * (Z.x + Zc.x), 0.5f * (Z.y - Zc.y));   // X1
    else
      X = make_float2(0.5f * (Z.y + Zc.y), 0.5f * (Zc.x - Z.x));   // X2
    F[((size_t)bc * WHv + w) * 256 + h0 + hh] = X;
  }
}

// Prep: split w1/w2 into hi/lo bf16 and swizzle into MFMA A-fragment order.
//   L=0 (w1): i = ks*32 + (lane>>4)*8 + j   (natural K-slots)
//   L=1 (w2): i = ks*32 + (j>>2)*16 + ((lane>>4)<<2) + (j&3)  (sigma so that
//             layer-2 B-frags equal layer-1 D-frags in-lane)
// o = m*16 + (lane&15). 1/256 forward-ortho folded into W1.
__global__ __launch_bounds__(256) void k_prep(const float* __restrict__ w1,
                                              const float* __restrict__ w2,
                                              __bf16* __restrict__ wp) {
  int idx = blockIdx.x * 256 + threadIdx.x;
  int j = idx & 7;
  int lane = (idx >> 3) & 63;
  int term = (idx >> 9) & 3;
  int t2 = idx >> 11;
  int m = t2 % 6; t2 /= 6;
  int ks = t2 % 3; t2 /= 3;
  int k = t2 & 7;
  int L = t2 >> 3;
  int i;
  if (L == 0) {
    i = ks * 32 + ((lane >> 4) << 3) + j;
  } else {
    i = ks * 32 + ((j >> 2) << 4) + ((lane >> 4) << 2) + (j & 3);
  }
  int o = (m << 4) + (lane & 15);
  const float* src = L ? w2 : w1;
  float v = src[(((size_t)k * BSv + i) * BSv + o) * 2 + (term >> 1)];
  if (L == 0) v *= (1.0f / 256.0f);
  __bf16 h = (__bf16)v;
  __bf16 r = (term & 1) ? (__bf16)(v - (float)h) : h;
  wp[idx] = r;
}

__device__ __forceinline__ void split6(float re, float im, int j,
                                       bf16x8& rh, bf16x8& rl,
                                       bf16x8& ih, bf16x8& il,
                                       bf16x8& ihn, bf16x8& iln) {
  __bf16 h = (__bf16)re;
  float hf = (float)h;
  rh[j] = h;
  rl[j] = (__bf16)(re - hf);
  __bf16 g = (__bf16)im;
  float gf = (float)g;
  ih[j] = g;
  il[j] = (__bf16)(im - gf);
  ihn[j] = (__bf16)(0.0f - gf);
  iln[j] = (__bf16)(gf - im);
}

__device__ __forceinline__ void mfma12(const bf16x8* q, int m,
                                       const bf16x8& rh, const bf16x8& rl,
                                       const bf16x8& ih, const bf16x8& il,
                                       const bf16x8& ihn, const bf16x8& iln,
                                       f32x4& ar, f32x4& ai) {
  bf16x8 wrh = q[(m * 4 + 0) * 64];
  bf16x8 wrl = q[(m * 4 + 1) * 64];
  bf16x8 wih = q[(m * 4 + 2) * 64];
  bf16x8 wil = q[(m * 4 + 3) * 64];
  ar = MFMA(wrh, rh, ar);
  ar = MFMA(wrh, rl, ar);
  ar = MFMA(wrl, rh, ar);
  ar = MFMA(wih, ihn, ar);
  ar = MFMA(wih, iln, ar);
  ar = MFMA(wil, ihn, ar);
  ai = MFMA(wrh, ih, ai);
  ai = MFMA(wrh, il, ai);
  ai = MFMA(wrl, ih, ai);
  ai = MFMA(wih, rh, ai);
  ai = MFMA(wih, rl, ai);
  ai = MFMA(wil, rh, ai);
}

// K3: per-mode block-diagonal complex MLP. One independent wave per
// (b, k, w, 16-h slice): no LDS, no barriers.
__global__ __launch_bounds__(256) void k_mix(cplx* __restrict__ F,
                                             const __bf16* __restrict__ WPg,
                                             const float* __restrict__ b1,
                                             const float* __restrict__ b2) {
  int tid = threadIdx.x;
  int lane = tid & 63;
  int gw = blockIdx.x * 4 + (tid >> 6);
  int ht = gw & 15; gw >>= 4;
  int w = gw % WHv; gw /= WHv;
  int k = gw & 7;
  int b = gw >> 3;
  int lg = lane >> 4;
  int hc = lane & 15;
  const size_t cstride = (size_t)WHv * 256;
  size_t base = ((size_t)(b * Cv + k * BSv) * WHv + w) * 256 + (ht << 4) + hc;

  const bf16x8* WPv = (const bf16x8*)WPg;
  const bf16x8* q1 = WPv + (size_t)k * (3 * 6 * 4 * 64) + lane;
  const bf16x8* q2 = WPv + (size_t)(8 + k) * (3 * 6 * 4 * 64) + lane;

  f32x4 acr[6], aci[6];
#pragma unroll
  for (int m = 0; m < 6; ++m) {
    acr[m] = (f32x4){0.0f, 0.0f, 0.0f, 0.0f};
    aci[m] = (f32x4){0.0f, 0.0f, 0.0f, 0.0f};
  }

#pragma unroll
  for (int ks = 0; ks < 3; ++ks) {
    bf16x8 rh, rl, ih, il, ihn, iln;
#pragma unroll
    for (int j = 0; j < 8; ++j) {
      cplx a = F[base + (size_t)(ks * 32 + (lg << 3) + j) * cstride];
      split6(a.x, a.y, j, rh, rl, ih, il, ihn, iln);
    }
    const bf16x8* q = q1 + ks * (6 * 4 * 64);
#pragma unroll
    for (int m = 0; m < 6; ++m)
      mfma12(q, m, rh, rl, ih, il, ihn, iln, acr[m], aci[m]);
  }

  const cplx* B1 = (const cplx*)b1 + k * BSv;
#pragma unroll
  for (int m = 0; m < 6; ++m) {
#pragma unroll
    for (int r = 0; r < 4; ++r) {
      cplx bb = B1[(m << 4) + (lg << 2) + r];
      acr[m][r] = fmaxf(acr[m][r] + bb.x, 0.0f);
      aci[m][r] = fmaxf(aci[m][r] + bb.y, 0.0f);
    }
  }

  f32x4 dcr[6], dci[6];
#pragma unroll
  for (int m = 0; m < 6; ++m) {
    dcr[m] = (f32x4){0.0f, 0.0f, 0.0f, 0.0f};
    dci[m] = (f32x4){0.0f, 0.0f, 0.0f, 0.0f};
  }
#pragma unroll
  for (int ks = 0; ks < 3; ++ks) {
    bf16x8 rh, rl, ih, il, ihn, iln;
#pragma unroll
    for (int j = 0; j < 8; ++j) {
      int mt = 2 * ks + (j >> 2);
      split6(acr[mt][j & 3], aci[mt][j & 3], j, rh, rl, ih, il, ihn, iln);
    }
    const bf16x8* q = q2 + ks * (6 * 4 * 64);
#pragma unroll
    for (int m = 0; m < 6; ++m)
      mfma12(q, m, rh, rl, ih, il, ihn, iln, dcr[m], dci[m]);
  }

  const cplx* B2 = (const cplx*)b2 + k * BSv;
#pragma unroll
  for (int m = 0; m < 6; ++m) {
#pragma unroll
    for (int r = 0; r < 4; ++r) {
      int o = (m << 4) + (lg << 2) + r;
      cplx bb = B2[o];
      float re = dcr[m][r] + bb.x;
      float im = dci[m][r] + bb.y;
      re = copysignf(fmaxf(fabsf(re) - 0.01f, 0.0f), re);
      im = copysignf(fmaxf(fabsf(im) - 0.01f, 0.0f), im);
      F[base + (size_t)o * cstride] = make_float2(re, im);
    }
  }
}

// K5: gather F tile, pack 2 rows (Z = X1 + i*X2) + Hermitian mirror into
// swizzled LDS (natural order), register DIT (scrambled read), write
// real parts * 1/256 + residual. 512 thr = 8 waves = 16 h-rows.
__global__ __launch_bounds__(512) void k_inv_row(const cplx* __restrict__ F,
                                                 const float* __restrict__ x,
                                                 float* __restrict__ out) {
  __shared__ cplx buf[8][258];
  int tid = threadIdx.x;
  int lane = tid & 63, wv = tid >> 6;
  cplx twA[3], twS[6];
  setup_tw<1>(lane, twA, twS);
  int bc = blockIdx.x >> 4;
  int h0 = (blockIdx.x & 15) << 4;
  for (int e = tid; e < WHv * 8; e += 512) {
    int w = e >> 3, p = e & 7;
    const cplx* src = &F[((size_t)bc * WHv + w) * 256 + h0 + 2 * p];
    float4 ab = *(const float4*)src;  // a = X1[w], b = X2[w]
    buf[p][swz(w)] = make_float2(ab.x - ab.w, ab.y + ab.z);      // X1 + i*X2
    if (w >= 1 && w <= 127) {
      int wm = 256 - w;
      buf[p][swz(wm)] = make_float2(ab.x + ab.w, ab.z - ab.y);   // conj-pack
    }
  }
  __syncthreads();
  cplx r[4];
  int f0 = brev6(lane) << 2;
#pragma unroll
  for (int q = 0; q < 4; ++q) r[q] = buf[wv][(f0 + q) ^ (f0 >> 4)];
  fft256_reg<1>(r, lane, twA, twS);
  const float* xr1 = x + ((size_t)bc * 256 + h0 + 2 * wv) * 256;
  const float* xr2 = xr1 + 256;
  float* o1 = out + ((size_t)bc * 256 + h0 + 2 * wv) * 256;
  float* o2 = o1 + 256;
#pragma unroll
  for (int p = 0; p < 4; ++p) {
    int n = (p << 6) + lane;
    o1[n] = r[p].x * (1.0f / 256.0f) + xr1[n];
    o2[n] = r[p].y * (1.0f / 256.0f) + xr2[n];
  }
}

extern "C" void kernel_launch(void* const* d_in, const int* in_sizes, int n_in,
                              void* d_out, int out_size, void* d_ws, size_t ws_size,
                              hipStream_t stream) {
  const float* x  = (const float*)d_in[0];
  const float* w1 = (const float*)d_in[1];
  const float* b1 = (const float*)d_in[2];
  const float* w2 = (const float*)d_in[3];
  const float* b2 = (const float*)d_in[4];
  float* out = (float*)d_out;
  cplx* F = (cplx*)d_ws;  // (B, C, Wh, H) complex fp32 = ~406 MB
  const size_t fbytes = (size_t)Bv * Cv * WHv * Hv * sizeof(cplx);
  __bf16* WP = (__bf16*)((char*)d_ws + fbytes);

  k_prep<<<2 * NBv * 3 * 6 * 4 * 64 * 8 / 256, 256, 0, stream>>>(w1, w2, WP);
  k_fwd_row<<<Bv * Cv * Hv / 16, 512, 0, stream>>>(x, F);
  k_col_fft_r<0><<<Bv * Cv * WHv / 16, 256, 0, stream>>>(F);
  k_mix<<<Bv * NBv * WHv * 16 / 4, 256, 0, stream>>>(F, WP, b1, b2);
  k_col_fft_r<1><<<Bv * Cv * WHv / 16, 256, 0, stream>>>(F);
  k_inv_row<<<Bv * Cv * Hv / 16, 512, 0, stream>>>(F, x, out);
}